// Round 4
// baseline (1597.891 us; speedup 1.0000x reference)
//
#include <hip/hip_runtime.h>
#include <hip/hip_bf16.h>

#define Bsz 256
#define Ssz 512
#define Fsz 64
#define Hsz 128
#define NG  512   // 4*H
#define CH  8     // steps per staged chunk

typedef unsigned short ushort_t;
typedef __attribute__((ext_vector_type(8))) short short8v;
typedef __attribute__((ext_vector_type(4))) float float4v;

__device__ __forceinline__ ushort_t f2bf(float f) {
  unsigned int b = __float_as_uint(f);
  return (ushort_t)((b + 0x7fffu + ((b >> 16) & 1u)) >> 16);
}
__device__ __forceinline__ float bf2f(ushort_t u) {
  return __uint_as_float(((unsigned int)u) << 16);
}
__device__ __forceinline__ float sigf(float v) { return 1.f / (1.f + __expf(-v)); }
__device__ __forceinline__ float tanhf_fast(float v) {
  float e = __expf(2.f * v);
  return 1.f - 2.f / (e + 1.f);
}
// raw barrier: drain LDS only, keep global loads in flight (no vmcnt drain)
__device__ __forceinline__ void bar_sync() {
  asm volatile("s_waitcnt lgkmcnt(0)" ::: "memory");
  __builtin_amdgcn_s_barrier();
  asm volatile("" ::: "memory");
}

// --- kernel 1: inv_denom[s] = 1 / (sum_{b,f} m[b,s,f] + 1e-5) ---
__global__ void denom_kernel(const float* __restrict__ m, float* __restrict__ inv_denom) {
  int s = blockIdx.x;
  int tid = threadIdx.x; // 256 threads, one per batch row
  const float4* mp = (const float4*)(m + ((size_t)tid * Ssz + s) * Fsz);
  float sum = 0.f;
#pragma unroll
  for (int i = 0; i < Fsz / 4; ++i) {
    float4 v = mp[i];
    sum += v.x + v.y + v.z + v.w;
  }
  for (int off = 32; off > 0; off >>= 1) sum += __shfl_xor(sum, off);
  __shared__ float red[4];
  if ((tid & 63) == 0) red[tid >> 6] = sum;
  __syncthreads();
  if (tid == 0) {
    float tot = red[0] + red[1] + red[2] + red[3];
    inv_denom[s] = 1.0f / (tot + 1e-5f);
  }
}

// --- kernel 2: pack [Wih | Whh] into bf16 MFMA B-fragments (validated r2/r3) ---
__global__ void pack_kernel(const float* __restrict__ Wih, const float* __restrict__ Whh,
                            ushort_t* __restrict__ Wpk) {
  int g = blockIdx.x * blockDim.x + threadIdx.x;   // 0..16383
  if (g >= 16384) return;
  int lane = g & 63, nt = (g >> 6) & 31, kt = g >> 11;
  int jout = nt * 16 + (lane & 15);
  int kbase = kt * 32 + ((lane >> 4) << 3);
  ushort_t* dst = Wpk + (size_t)g * 8;
#pragma unroll
  for (int j = 0; j < 8; ++j) {
    int k = kbase + j;
    float w = (k < 128) ? Wih[jout * 128 + k] : Whh[jout * 128 + (k - 128)];
    dst[j] = f2bf(w);
  }
}

// --- kernel 3: gamma_h precompute (validated r3) ---
__global__ void gh_kernel(const float* __restrict__ t, const float* __restrict__ Wdh,
                          const float* __restrict__ bdh, ushort_t* __restrict__ gh) {
  const int tid = threadIdx.x;
  const int lane = tid & 63, wv = tid >> 6;
  const int row0 = blockIdx.x * 64;
  __shared__ __align__(16) ushort_t st[64][72];
  __shared__ __align__(16) ushort_t sO[64][136];
  __shared__ float sbdh[128];
  if (tid < 128) sbdh[tid] = bdh[tid];
  short8v Bf[2][8];
#pragma unroll
  for (int kt = 0; kt < 2; ++kt)
#pragma unroll
    for (int nt = 0; nt < 8; ++nt) {
      int col = nt * 16 + (lane & 15);
      int k0 = kt * 32 + ((lane >> 4) << 3);
      float4 wa = *(const float4*)(Wdh + col * 64 + k0);
      float4 wb = *(const float4*)(Wdh + col * 64 + k0 + 4);
      short8v bb;
      bb[0] = (short)f2bf(wa.x); bb[1] = (short)f2bf(wa.y);
      bb[2] = (short)f2bf(wa.z); bb[3] = (short)f2bf(wa.w);
      bb[4] = (short)f2bf(wb.x); bb[5] = (short)f2bf(wb.y);
      bb[6] = (short)f2bf(wb.z); bb[7] = (short)f2bf(wb.w);
      Bf[kt][nt] = bb;
    }
  const float* tb = t + (size_t)row0 * 64;
  {
    int r = tid >> 2, c0 = (tid & 3) * 16;
#pragma unroll
    for (int q = 0; q < 4; ++q) {
      float4 v = *(const float4*)(tb + r * 64 + c0 + q * 4);
      st[r][c0 + q * 4 + 0] = f2bf(v.x);
      st[r][c0 + q * 4 + 1] = f2bf(v.y);
      st[r][c0 + q * 4 + 2] = f2bf(v.z);
      st[r][c0 + q * 4 + 3] = f2bf(v.w);
    }
  }
  __syncthreads();
  float4v acc[8] = {};
#pragma unroll
  for (int kt = 0; kt < 2; ++kt) {
    int r = wv * 16 + (lane & 15);
    int k0 = kt * 32 + ((lane >> 4) << 3);
    short8v a = *(const short8v*)&st[r][k0];
#pragma unroll
    for (int nt = 0; nt < 8; ++nt)
      acc[nt] = __builtin_amdgcn_mfma_f32_16x16x32_bf16(a, Bf[kt][nt], acc[nt], 0, 0, 0);
  }
#pragma unroll
  for (int nt = 0; nt < 8; ++nt)
#pragma unroll
    for (int rr = 0; rr < 4; ++rr) {
      int col = nt * 16 + (lane & 15);
      int row = wv * 16 + ((lane >> 4) << 2) + rr;
      float v = acc[nt][rr] + sbdh[col];
      sO[row][col] = f2bf(__expf(-fmaxf(0.f, v)));
    }
  __syncthreads();
  {
    int r = tid >> 2, c0 = (tid & 3) * 32;
    const uint4* src = (const uint4*)&sO[r][c0];
    uint4* dst = (uint4*)(gh + (size_t)(row0 + r) * 128 + c0);
#pragma unroll
    for (int q = 0; q < 4; ++q) dst[q] = src[q];
  }
}

// --- kernel 4: beta precompute (validated r3) ---
__global__ void beta_kernel(const float* __restrict__ t, const float* __restrict__ m,
                            const float* __restrict__ Wdm, const float* __restrict__ bdm,
                            const float* __restrict__ Wwc, const float* __restrict__ bwc,
                            ushort_t* __restrict__ beta) {
  const int tid = threadIdx.x;
  const int lane = tid & 63, wv = tid >> 6;
  const int row0 = blockIdx.x * 64;
  __shared__ __align__(16) ushort_t sA[64][136];
  __shared__ __align__(16) ushort_t sO[64][72];
  __shared__ float sdw[64], sbd[64], sbwc[64];
  if (tid < 64) {
    sdw[tid] = Wdm[tid * 64 + tid];
    sbd[tid] = bdm[tid];
    sbwc[tid] = bwc[tid];
  }
  short8v Bf[4][4];
#pragma unroll
  for (int kt = 0; kt < 4; ++kt)
#pragma unroll
    for (int nt = 0; nt < 4; ++nt) {
      int col = nt * 16 + (lane & 15);
      int k0 = kt * 32 + ((lane >> 4) << 3);
      float4 wa = *(const float4*)(Wwc + col * 128 + k0);
      float4 wb = *(const float4*)(Wwc + col * 128 + k0 + 4);
      short8v bb;
      bb[0] = (short)f2bf(wa.x); bb[1] = (short)f2bf(wa.y);
      bb[2] = (short)f2bf(wa.z); bb[3] = (short)f2bf(wa.w);
      bb[4] = (short)f2bf(wb.x); bb[5] = (short)f2bf(wb.y);
      bb[6] = (short)f2bf(wb.z); bb[7] = (short)f2bf(wb.w);
      Bf[kt][nt] = bb;
    }
  __syncthreads();
  {
    int r = tid >> 2, c0 = (tid & 3) * 16;
    const float* tb = t + (size_t)row0 * 64;
    const float* mb = m + (size_t)row0 * 64;
#pragma unroll
    for (int q = 0; q < 4; ++q) {
      float4 tv = *(const float4*)(tb + r * 64 + c0 + q * 4);
      float4 mv = *(const float4*)(mb + r * 64 + c0 + q * 4);
      int c = c0 + q * 4;
      sA[r][c + 0] = f2bf(__expf(-fmaxf(0.f, tv.x * sdw[c + 0] + sbd[c + 0])));
      sA[r][c + 1] = f2bf(__expf(-fmaxf(0.f, tv.y * sdw[c + 1] + sbd[c + 1])));
      sA[r][c + 2] = f2bf(__expf(-fmaxf(0.f, tv.z * sdw[c + 2] + sbd[c + 2])));
      sA[r][c + 3] = f2bf(__expf(-fmaxf(0.f, tv.w * sdw[c + 3] + sbd[c + 3])));
      sA[r][64 + c + 0] = f2bf(mv.x);
      sA[r][64 + c + 1] = f2bf(mv.y);
      sA[r][64 + c + 2] = f2bf(mv.z);
      sA[r][64 + c + 3] = f2bf(mv.w);
    }
  }
  __syncthreads();
  float4v acc[4] = {};
#pragma unroll
  for (int kt = 0; kt < 4; ++kt) {
    int r = wv * 16 + (lane & 15);
    int k0 = kt * 32 + ((lane >> 4) << 3);
    short8v a = *(const short8v*)&sA[r][k0];
#pragma unroll
    for (int nt = 0; nt < 4; ++nt)
      acc[nt] = __builtin_amdgcn_mfma_f32_16x16x32_bf16(a, Bf[kt][nt], acc[nt], 0, 0, 0);
  }
#pragma unroll
  for (int nt = 0; nt < 4; ++nt)
#pragma unroll
    for (int rr = 0; rr < 4; ++rr) {
      int col = nt * 16 + (lane & 15);
      int row = wv * 16 + ((lane >> 4) << 2) + rr;
      sO[row][col] = f2bf(acc[nt][rr] + sbwc[col]);
    }
  __syncthreads();
  {
    int r = tid >> 2, c0 = (tid & 3) * 16;
    const uint4* src = (const uint4*)&sO[r][c0];
    uint4* dst = (uint4*)(beta + (size_t)(row0 + r) * 64 + c0);
    dst[0] = src[0];
    dst[1] = src[1];
  }
}

// --- kernel 5: recurrence. 1 block/row, 512 threads, 3 raw barriers/step. ---
// V layout (K=256): k 0..63 = cl_c, 64..127 = m, 128..255 = h (decayed)
// gates nt-map: wave w owns nt = {w, w+8, w+16, w+24} -> acc[0..3] = i,f,g,o for h[16w..16w+16)
__launch_bounds__(512, 1)
__global__ void rits_kernel(
    const float* __restrict__ x, const float* __restrict__ m,
    const float* __restrict__ Wtr, const float* __restrict__ btr,
    const float* __restrict__ Wfr, const float* __restrict__ bfr,
    const float* __restrict__ bih, const float* __restrict__ bhh,
    const ushort_t* __restrict__ Wpk, const float* __restrict__ inv_denom,
    const ushort_t* __restrict__ ghp, const ushort_t* __restrict__ betap,
    float* __restrict__ out_imp, float* __restrict__ out_loss)
{
  const int b = blockIdx.x;
  const int tid = threadIdx.x;
  const int lane = tid & 63;
  const int wv = tid >> 6;
  const int l15 = lane & 15;
  const int kg = lane >> 4;

  __shared__ float sIdn[Ssz];
  __shared__ __align__(16) ushort_t sHh[Hsz];     // decayed h, bf16
  __shared__ __align__(16) ushort_t sXcF[Fsz];    // xl_c frag (A for Wfr)
  __shared__ __align__(16) ushort_t sClcF[Fsz];   // cl_c frag (A for gates kt0,1)
  __shared__ float sXlhP[2][Fsz];                 // Wtr partials (waves 1,3)
  __shared__ __align__(16) float    sXb[2][CH][Fsz];   // staged x (f32)
  __shared__ __align__(16) ushort_t sMb[2][CH][Fsz];   // staged m (bf16, exact 0/1)
  __shared__ __align__(16) ushort_t sBb[2][CH][Fsz];   // staged beta (bf16)
  __shared__ __align__(16) ushort_t sGb[2][CH][Hsz];   // staged gamma_h (shifted +1)

  sIdn[tid] = inv_denom[tid];
  if (tid < Hsz) sHh[tid] = 0;

  // gates B-frags (nt = wv + 8n) + bias
  const short8v* wp = (const short8v*)Wpk;
  short8v Bf[8][4];
#pragma unroll
  for (int kt = 0; kt < 8; ++kt)
#pragma unroll
    for (int n = 0; n < 4; ++n)
      Bf[kt][n] = wp[((kt * 32 + wv + 8 * n) << 6) + lane];
  float gb[4];
#pragma unroll
  for (int n = 0; n < 4; ++n) {
    int j = (wv + 8 * n) * 16 + l15;
    gb[n] = bih[j] + bhh[j];
  }

  // union weight frags: wave1 = Wtr k0..63, wave3 = Wtr k64..127, wave2 = Wfr (diag 0)
  short8v uW[8];
  float btr_r[4] = {0.f, 0.f, 0.f, 0.f}, bfr_r[4] = {0.f, 0.f, 0.f, 0.f};
  if (wv == 1 || wv == 3) {
    const int ktb = (wv == 1) ? 0 : 2;
#pragma unroll
    for (int kt = 0; kt < 2; ++kt)
#pragma unroll
      for (int n = 0; n < 4; ++n) {
        int col = n * 16 + l15;
        int k0 = (ktb + kt) * 32 + kg * 8;
        short8v bb;
#pragma unroll
        for (int j = 0; j < 8; ++j) bb[j] = (short)f2bf(Wtr[col * 128 + k0 + j]);
        uW[kt * 4 + n] = bb;
      }
  } else if (wv == 2) {
#pragma unroll
    for (int kt = 0; kt < 2; ++kt)
#pragma unroll
      for (int n = 0; n < 4; ++n) {
        int col = n * 16 + l15;
        int k0 = kt * 32 + kg * 8;
        short8v bb;
#pragma unroll
        for (int j = 0; j < 8; ++j) {
          int k = k0 + j;
          bb[j] = (k == col) ? (short)0 : (short)f2bf(Wfr[col * 64 + k]);
        }
        uW[kt * 4 + n] = bb;
      }
#pragma unroll
    for (int n = 0; n < 4; ++n) {
      btr_r[n] = btr[n * 16 + l15];
      bfr_r[n] = bfr[n * 16 + l15];
    }
  }

  const float* xp = x + (size_t)b * Ssz * Fsz;
  const float* mp = m + (size_t)b * Ssz * Fsz;
  const ushort_t* ghb = ghp + (size_t)b * Ssz * Hsz;
  const ushort_t* beb = betap + (size_t)b * Ssz * Fsz;
  float* op = out_imp + (size_t)b * Ssz * Fsz;

  // prologue: stage chunk 0 (x/m/beta steps 0..7; gh steps 1..8)
  {
    float x0 = xp[tid], m0 = mp[tid];
    ushort_t b0 = beb[tid];
    int st0 = 1 + (tid >> 7);
    int st1 = st0 + 4;
    ushort_t g0 = ghb[(size_t)st0 * Hsz + (tid & 127)];
    ushort_t g1 = ghb[(size_t)st1 * Hsz + (tid & 127)];
    sXb[0][tid >> 6][tid & 63] = x0;
    sMb[0][tid >> 6][tid & 63] = f2bf(m0);
    sBb[0][tid >> 6][tid & 63] = b0;
    sGb[0][tid >> 7][tid & 127] = g0;
    sGb[0][4 + (tid >> 7)][tid & 127] = g1;
  }
  __syncthreads();

  float lacc = 0.f;
  float c_reg = 0.f;
  float x_r = 0.f, m_r = 0.f;
  ushort_t be_r = 0, gh_r0 = 0, gh_r1 = 0;

  for (int s = 0; s < Ssz; ++s) {
    const int p = (s >> 3) & 1, sc = s & 7;

    // ================= P1 =================
    // issue next-chunk loads (stay in flight across raw barriers)
    if (sc == 0 && s + CH < Ssz) {
      int base = (s + CH) * Fsz;
      x_r = xp[base + tid];
      m_r = mp[base + tid];
      be_r = beb[base + tid];
      int st0 = s + CH + 1 + (tid >> 7);
      int st1 = st0 + 4;
      if (st0 > Ssz - 1) st0 = Ssz - 1;
      if (st1 > Ssz - 1) st1 = Ssz - 1;
      gh_r0 = ghb[(size_t)st0 * Hsz + (tid & 127)];
      gh_r1 = ghb[(size_t)st1 * Hsz + (tid & 127)];
    }
    // A-frags (4-distinct-address reads)
    const char* hbase = (const char*)sHh + kg * 16;
    short8v ah0 = *(const short8v*)(hbase);
    short8v ah1 = *(const short8v*)(hbase + 64);
    short8v ah2 = *(const short8v*)(hbase + 128);
    short8v ah3 = *(const short8v*)(hbase + 192);
    const char* mbase = (const char*)sMb[p][sc] + kg * 16;
    short8v am0 = *(const short8v*)(mbase);
    short8v am1 = *(const short8v*)(mbase + 64);

    float4v acc[4];
#pragma unroll
    for (int n = 0; n < 4; ++n) acc[n] = (float4v){gb[n], gb[n], gb[n], gb[n]};
#pragma unroll
    for (int n = 0; n < 4; ++n) {
      acc[n] = __builtin_amdgcn_mfma_f32_16x16x32_bf16(am0, Bf[2][n], acc[n], 0, 0, 0);
      acc[n] = __builtin_amdgcn_mfma_f32_16x16x32_bf16(am1, Bf[3][n], acc[n], 0, 0, 0);
      acc[n] = __builtin_amdgcn_mfma_f32_16x16x32_bf16(ah0, Bf[4][n], acc[n], 0, 0, 0);
      acc[n] = __builtin_amdgcn_mfma_f32_16x16x32_bf16(ah1, Bf[5][n], acc[n], 0, 0, 0);
      acc[n] = __builtin_amdgcn_mfma_f32_16x16x32_bf16(ah2, Bf[6][n], acc[n], 0, 0, 0);
      acc[n] = __builtin_amdgcn_mfma_f32_16x16x32_bf16(ah3, Bf[7][n], acc[n], 0, 0, 0);
    }
    if (wv == 1 || wv == 3) {
      short8v a0 = (wv == 1) ? ah0 : ah2;
      short8v a1 = (wv == 1) ? ah1 : ah3;
      float4v xacc[4];
#pragma unroll
      for (int n = 0; n < 4; ++n) xacc[n] = (float4v){0.f, 0.f, 0.f, 0.f};
#pragma unroll
      for (int n = 0; n < 4; ++n) {
        xacc[n] = __builtin_amdgcn_mfma_f32_16x16x32_bf16(a0, uW[n], xacc[n], 0, 0, 0);
        xacc[n] = __builtin_amdgcn_mfma_f32_16x16x32_bf16(a1, uW[4 + n], xacc[n], 0, 0, 0);
      }
      if (lane < 16) {
        const int w = (wv == 1) ? 0 : 1;
#pragma unroll
        for (int n = 0; n < 4; ++n) sXlhP[w][n * 16 + lane] = xacc[n][0];
      }
    }
    bar_sync();

    // ================= P2 (wave 2 solo) =================
    if (wv == 2) {
      const float idn = sIdn[s];
      float xlh[4], xv[4], mv[4], bev[4], xlc[4];
#pragma unroll
      for (int n = 0; n < 4; ++n) {
        int f = n * 16 + l15;
        xlh[n] = sXlhP[0][f] + sXlhP[1][f] + btr_r[n];
        xv[n] = sXb[p][sc][f];
        mv[n] = bf2f(sMb[p][sc][f]);
        bev[n] = bf2f(sBb[p][sc][f]);
        xlc[n] = mv[n] * xv[n] + (1.f - mv[n]) * xlh[n];
      }
      if (lane < 16) {
#pragma unroll
        for (int n = 0; n < 4; ++n) {
          float d = xv[n] - xlh[n];
          lacc += d * d * mv[n] * idn;          // loss term 1
          sXcF[n * 16 + lane] = f2bf(xlc[n]);
        }
      }
      const char* xbase = (const char*)sXcF + kg * 16;
      short8v ax0 = *(const short8v*)(xbase);
      short8v ax1 = *(const short8v*)(xbase + 64);
      float4v zac[4];
#pragma unroll
      for (int n = 0; n < 4; ++n) zac[n] = (float4v){0.f, 0.f, 0.f, 0.f};
#pragma unroll
      for (int n = 0; n < 4; ++n) {
        zac[n] = __builtin_amdgcn_mfma_f32_16x16x32_bf16(ax0, uW[n], zac[n], 0, 0, 0);
        zac[n] = __builtin_amdgcn_mfma_f32_16x16x32_bf16(ax1, uW[4 + n], zac[n], 0, 0, 0);
      }
      if (lane < 16) {
#pragma unroll
        for (int n = 0; n < 4; ++n) {
          float zl = zac[n][0] + bfr_r[n];
          float clh = bev[n] * zl + (1.f - bev[n]) * xlh[n];
          float d2 = xv[n] - zl, d3 = xv[n] - clh;
          lacc += (d2 * d2 + d3 * d3) * mv[n] * idn;   // loss terms 2+3
          float clc = mv[n] * xv[n] + (1.f - mv[n]) * clh;
          sClcF[n * 16 + lane] = f2bf(clc);
          op[s * Fsz + n * 16 + lane] = clc;
        }
      }
    }
    bar_sync();

    // ================= P3 =================
    const char* cbase = (const char*)sClcF + kg * 16;
    short8v ac0 = *(const short8v*)(cbase);
    short8v ac1 = *(const short8v*)(cbase + 64);
#pragma unroll
    for (int n = 0; n < 4; ++n) {
      acc[n] = __builtin_amdgcn_mfma_f32_16x16x32_bf16(ac0, Bf[0][n], acc[n], 0, 0, 0);
      acc[n] = __builtin_amdgcn_mfma_f32_16x16x32_bf16(ac1, Bf[1][n], acc[n], 0, 0, 0);
    }
    if (lane < 16) {   // in-phase LSTM: acc[0..3][0] = i,f,g,o for hh
      const int hh = wv * 16 + lane;
      float cc = sigf(acc[1][0]) * c_reg + sigf(acc[0][0]) * tanhf_fast(acc[2][0]);
      c_reg = cc;
      float hn = sigf(acc[3][0]) * tanhf_fast(cc);
      float hv = hn * bf2f(sGb[p][sc][hh]);   // pre-decay with gamma_h(s+1)
      sHh[hh] = f2bf(hv);
    }
    if (sc == 7 && s + 1 < Ssz) {   // write staged chunk
      const int q = p ^ 1;
      sXb[q][tid >> 6][tid & 63] = x_r;
      sMb[q][tid >> 6][tid & 63] = f2bf(m_r);
      sBb[q][tid >> 6][tid & 63] = be_r;
      sGb[q][tid >> 7][tid & 127] = gh_r0;
      sGb[q][4 + (tid >> 7)][tid & 127] = gh_r1;
    }
    bar_sync();
  }

  // loss reduction (wave 2, lanes 0..15 hold partials)
  if (wv == 2 && lane < 16) {
    lacc += __shfl_xor(lacc, 1);
    lacc += __shfl_xor(lacc, 2);
    lacc += __shfl_xor(lacc, 4);
    lacc += __shfl_xor(lacc, 8);
    if (lane == 0) atomicAdd(out_loss, lacc * (1.0f / Ssz));
  }
}

extern "C" void kernel_launch(void* const* d_in, const int* in_sizes, int n_in,
                              void* d_out, int out_size, void* d_ws, size_t ws_size,
                              hipStream_t stream) {
  const float* x   = (const float*)d_in[0];
  const float* m   = (const float*)d_in[1];
  const float* t   = (const float*)d_in[2];
  const float* Wdh = (const float*)d_in[3];
  const float* bdh = (const float*)d_in[4];
  const float* Wdm = (const float*)d_in[5];
  const float* bdm = (const float*)d_in[6];
  const float* Wtr = (const float*)d_in[7];
  const float* btr = (const float*)d_in[8];
  const float* Wfr = (const float*)d_in[9];
  const float* bfr = (const float*)d_in[10];
  const float* Wwc = (const float*)d_in[11];
  const float* bwc = (const float*)d_in[12];
  const float* Wih = (const float*)d_in[13];
  const float* Whh = (const float*)d_in[14];
  const float* bih = (const float*)d_in[15];
  const float* bhh = (const float*)d_in[16];

  char* ws = (char*)d_ws;
  float* inv_denom = (float*)ws;                       // 2 KiB
  ushort_t* Wpk    = (ushort_t*)(ws + 2048);           // 256 KiB
  ushort_t* gh_ws  = (ushort_t*)(ws + 264192);         // 32 MiB  (B*S*128 bf16)
  ushort_t* be_ws  = (ushort_t*)(ws + 264192 + (size_t)Bsz * Ssz * 128 * 2);  // 16 MiB
  float* out_f = (float*)d_out;
  float* out_loss = out_f + (size_t)Bsz * Ssz * Fsz;

  denom_kernel<<<Ssz, 256, 0, stream>>>(m, inv_denom);
  pack_kernel<<<64, 256, 0, stream>>>(Wih, Whh, Wpk);
  gh_kernel<<<(Bsz * Ssz) / 64, 256, 0, stream>>>(t, Wdh, bdh, gh_ws);
  beta_kernel<<<(Bsz * Ssz) / 64, 256, 0, stream>>>(t, m, Wdm, bdm, Wwc, bwc, be_ws);
  hipMemsetAsync(out_loss, 0, sizeof(float), stream);
  rits_kernel<<<Bsz, 512, 0, stream>>>(x, m, Wtr, btr, Wfr, bfr, bih, bhh,
                                       Wpk, inv_denom, gh_ws, be_ws, out_f, out_loss);
}